// Round 5
// baseline (453.268 us; speedup 1.0000x reference)
//
#include <hip/hip_runtime.h>
#include <math.h>

typedef __bf16 bf16_t;
typedef bf16_t bf16x8 __attribute__((ext_vector_type(8)));
typedef float  floatx4 __attribute__((ext_vector_type(4)));

#define MFMA16(a, b, c) __builtin_amdgcn_mfma_f32_16x16x32_bf16((a), (b), (c), 0, 0, 0)

// Problem constants
constexpr int NTOT = 256 * 512;   // 131072 samples
constexpr int CDIM = 256;         // K for all GEMMs

// ws: flat stream of 88 weight tiles in USE ORDER; tile = 16 output cols x 256 k
// in MFMA B-fragment order: tile[ks][lane][j] (8 KB). Wave B-load = contiguous 1 KB.
//   tiles  0..15 : w1a   (phase A)
//   tiles 16..19 : wb1   (phase B1)
//   tiles 20..51 : w1b   (phase B2)
//   tiles 52..67 : w2a   (phase C)
//   tiles 68..71 : w2b   (phase D)
//   tiles 72..87 : wb2a  (phase E)
constexpr int N_TILES  = 88;
constexpr int WS_ELEMS = N_TILES * 4096;
constexpr int N_GROUPS = 44;      // staging group = 2 tiles = 16 KB

// ---------------------------------------------------------------------------
__global__ void prep_weights(const float* __restrict__ w1a, const float* __restrict__ w1b,
                             const float* __restrict__ w2a, const float* __restrict__ w2b,
                             const float* __restrict__ wb1, const float* __restrict__ wb2a,
                             bf16_t* __restrict__ ws) {
  int idx = blockIdx.x * 256 + threadIdx.x;
  if (idx >= WS_ELEMS) return;
  int t   = idx >> 12;       // tile
  int rel = idx & 4095;
  const float* src; int dout; int ct;
  if      (t < 16) { src = w1a;  dout = 256; ct = t; }
  else if (t < 20) { src = wb1;  dout = 64;  ct = t - 16; }
  else if (t < 52) { src = w1b;  dout = 512; ct = t - 20; }
  else if (t < 68) { src = w2a;  dout = 256; ct = t - 52; }
  else if (t < 72) { src = w2b;  dout = 64;  ct = t - 68; }
  else             { src = wb2a; dout = 256; ct = t - 72; }
  int j    = rel & 7;
  int lane = (rel >> 3) & 63;
  int ks   = rel >> 9;
  int o = ct * 16 + (lane & 15);
  int k = ks * 32 + (lane >> 4) * 8 + j;
  ws[idx] = (bf16_t)src[(size_t)k * dout + o];
}

// async global->LDS, 16 B per lane; LDS dest = wave-uniform base + lane*16
__device__ __forceinline__ void gload_lds16(const bf16_t* g, bf16_t* l) {
  __builtin_amdgcn_global_load_lds(
      (const __attribute__((address_space(1))) unsigned int*)g,
      (__attribute__((address_space(3))) unsigned int*)l, 16, 0, 0);
}

// ---------------------------------------------------------------------------
// Block = 4 waves = 128 rows, grid = 1024. All 4 waves share weight tiles
// staged once per block into LDS (L2 weight traffic /4). Schedule per group:
//   __syncthreads();  stage(g+1);  compute(g)
// so each wave's DMA has a full compute-group before its drain at the next
// barrier (drain ~free). 44 barriers total, identical across waves.
// ---------------------------------------------------------------------------
__global__ __launch_bounds__(256, 2)
void mixing_fused(const float* __restrict__ q,     // [N,8]
                  const float* __restrict__ st,    // [N,256]
                  const bf16_t* __restrict__ W,    // ws (tile stream)
                  const float* __restrict__ b1a, const float* __restrict__ b1b,
                  const float* __restrict__ b2a, const float* __restrict__ b2b,
                  const float* __restrict__ bb1,
                  const float* __restrict__ bb2a,
                  const float* __restrict__ wb2b, const float* __restrict__ bb2b,
                  float* __restrict__ out) {
  __shared__ __align__(16) bf16_t wbuf[2][8192];   // 2 x 16 KB weight groups
  __shared__ __align__(16) bf16_t t_s[4][2][32][36]; // per-wave bounce (transpose)
  __shared__ __align__(16) float  q_s[4][256];     // per-wave q staging

  const int tid  = threadIdx.x;
  const int wid  = tid >> 6;
  const int lane = tid & 63;
  const int l15  = lane & 15;
  const int quad = lane >> 4;
  const int m0   = blockIdx.x * 128 + wid * 32;

  // wave-cooperative stage of group g (16 KB) into wbuf[g&1]
  auto stage = [&](int g) {
    const bf16_t* src = W + (size_t)g * 8192 + wid * 2048 + lane * 8;
    bf16_t* dst = &wbuf[g & 1][wid * 2048];
#pragma unroll
    for (int i = 0; i < 4; ++i)
      gload_lds16(src + i * 512, dst + i * 512);
  };

  // ---- wave-local q staging ----
  *(float4*)&q_s[wid][lane * 4] = *(const float4*)(q + (size_t)m0 * 8 + lane * 4);

  // ---- st A-fragments straight from global (coalesced), cvt to bf16 ----
  bf16x8 sA[2][8];
#pragma unroll
  for (int rt = 0; rt < 2; ++rt) {
    const float* rp = st + (size_t)(m0 + rt * 16 + l15) * CDIM;
#pragma unroll
    for (int ks = 0; ks < 8; ++ks) {
      int k0 = ks * 32 + quad * 8;
      float4 f0 = *(const float4*)(rp + k0);
      float4 f1 = *(const float4*)(rp + k0 + 4);
      bf16x8 v;
      v[0] = (bf16_t)f0.x; v[1] = (bf16_t)f0.y; v[2] = (bf16_t)f0.z; v[3] = (bf16_t)f0.w;
      v[4] = (bf16_t)f1.x; v[5] = (bf16_t)f1.y; v[6] = (bf16_t)f1.z; v[7] = (bf16_t)f1.w;
      sA[rt][ks] = v;
    }
  }

  // GEMM: 16-col tile h (0/1) of LDS group buffer `buf`, both row tiles
  auto gemmL = [&](int buf, int h, const bf16x8 (&A)[2][8], floatx4 (&acc)[2]) {
    floatx4 z = {0.f, 0.f, 0.f, 0.f};
    acc[0] = z; acc[1] = z;
#pragma unroll
    for (int kk = 0; kk < 8; ++kk) {
      bf16x8 b = *(const bf16x8*)&wbuf[buf][h * 4096 + kk * 512 + lane * 8];
      acc[0] = MFMA16(A[0][kk], b, acc[0]);
      acc[1] = MFMA16(A[1][kk], b, acc[1]);
    }
  };

  stage(0);

  bf16x8 hA[2][8];

  // ================= Phase A: H1 = elu(st @ w1a + b1a)   groups 0..7 =========
#pragma unroll 1
  for (int ks = 0; ks < 8; ++ks) {
    __syncthreads();
    stage(ks + 1);
    const int buf = ks & 1;
#pragma unroll
    for (int h = 0; h < 2; ++h) {
      int ct = 2 * ks + h;
      floatx4 acc[2];
      gemmL(buf, h, sA, acc);
      float bias = b1a[ct * 16 + l15];
#pragma unroll
      for (int rt = 0; rt < 2; ++rt)
#pragma unroll
        for (int i = 0; i < 4; ++i) {
          float v = acc[rt][i] + bias;
          v = v > 0.f ? v : (__expf(v) - 1.f);
          t_s[wid][buf][rt * 16 + quad * 4 + i][h * 16 + l15] = (bf16_t)v;
        }
    }
#pragma unroll
    for (int rt = 0; rt < 2; ++rt)
      hA[rt][ks] = *(const bf16x8*)&t_s[wid][buf][rt * 16 + l15][quad * 8];
  }

  // ================= Phase B1: hidden = st @ wb1 + bb1   groups 8..9 =========
  floatx4 hid[2][4];
#pragma unroll 1
  for (int gg = 0; gg < 2; ++gg) {
    __syncthreads();
    stage(9 + gg);
    const int buf = gg & 1;
#pragma unroll
    for (int h = 0; h < 2; ++h) {
      int et = 2 * gg + h;
      floatx4 acc[2];
      gemmL(buf, h, sA, acc);
      float bias = bb1[et * 16 + l15];
      hid[0][et] = acc[0] + bias;
      hid[1][et] = acc[1] + bias;
    }
  }

  // ====== Phase B2: W1 = |H1 @ w1b + b1b|; hidden += q.*W1   groups 10..25 ===
#pragma unroll 1
  for (int gg = 0; gg < 16; ++gg) {
    __syncthreads();
    stage(11 + gg);
    const int buf = gg & 1;
#pragma unroll
    for (int h = 0; h < 2; ++h) {
      int ct = 2 * gg + h;
      int a = ct >> 2, et = ct & 3;
      floatx4 acc[2];
      gemmL(buf, h, hA, acc);
      float bias = b1b[ct * 16 + l15];
#pragma unroll
      for (int rt = 0; rt < 2; ++rt)
#pragma unroll
        for (int i = 0; i < 4; ++i) {
          float w1v = fabsf(acc[rt][i] + bias);
          float qv  = q_s[wid][(rt * 16 + quad * 4 + i) * 8 + a];
          hid[rt][et][i] += qv * w1v;
        }
    }
  }
  // relu
#pragma unroll
  for (int rt = 0; rt < 2; ++rt)
#pragma unroll
    for (int et = 0; et < 4; ++et)
#pragma unroll
      for (int i = 0; i < 4; ++i) hid[rt][et][i] = fmaxf(hid[rt][et][i], 0.f);

  // ================= Phase C: H2 = elu(st @ w2a + b2a)   groups 26..33 =======
#pragma unroll 1
  for (int ks = 0; ks < 8; ++ks) {
    __syncthreads();
    stage(27 + ks);
    const int buf = ks & 1;
#pragma unroll
    for (int h = 0; h < 2; ++h) {
      int ct = 2 * ks + h;
      floatx4 acc[2];
      gemmL(buf, h, sA, acc);
      float bias = b2a[ct * 16 + l15];
#pragma unroll
      for (int rt = 0; rt < 2; ++rt)
#pragma unroll
        for (int i = 0; i < 4; ++i) {
          float v = acc[rt][i] + bias;
          v = v > 0.f ? v : (__expf(v) - 1.f);
          t_s[wid][buf][rt * 16 + quad * 4 + i][h * 16 + l15] = (bf16_t)v;
        }
    }
#pragma unroll
    for (int rt = 0; rt < 2; ++rt)
      hA[rt][ks] = *(const bf16x8*)&t_s[wid][buf][rt * 16 + l15][quad * 8];
  }

  // ====== Phase D: W2 = |H2 @ w2b + b2b|; pj = sum_e hidden*W2  groups 34..35 =
  float pj[2][4] = {{0.f, 0.f, 0.f, 0.f}, {0.f, 0.f, 0.f, 0.f}};
#pragma unroll 1
  for (int gg = 0; gg < 2; ++gg) {
    __syncthreads();
    stage(35 + gg);
    const int buf = gg & 1;
#pragma unroll
    for (int h = 0; h < 2; ++h) {
      int et = 2 * gg + h;
      floatx4 acc[2];
      gemmL(buf, h, hA, acc);
      float bias = b2b[et * 16 + l15];
#pragma unroll
      for (int rt = 0; rt < 2; ++rt)
#pragma unroll
        for (int i = 0; i < 4; ++i) {
          float w2v = fabsf(acc[rt][i] + bias);
          pj[rt][i] += hid[rt][et][i] * w2v;
        }
    }
  }

  // == Phase E: HB = elu(st @ wb2a + bb2a); pb = HB @ wb2b   groups 36..43 ====
  float pb[2][4] = {{0.f, 0.f, 0.f, 0.f}, {0.f, 0.f, 0.f, 0.f}};
#pragma unroll 1
  for (int gg = 0; gg < 8; ++gg) {
    __syncthreads();
    if (gg < 7) stage(37 + gg);
    const int buf = gg & 1;
#pragma unroll
    for (int h = 0; h < 2; ++h) {
      int ct = 2 * gg + h;
      floatx4 acc[2];
      gemmL(buf, h, sA, acc);
      float bias = bb2a[ct * 16 + l15];
      float wv   = wb2b[ct * 16 + l15];
#pragma unroll
      for (int rt = 0; rt < 2; ++rt)
#pragma unroll
        for (int i = 0; i < 4; ++i) {
          float v = acc[rt][i] + bias;
          v = v > 0.f ? v : (__expf(v) - 1.f);
          pb[rt][i] += v * wv;
        }
    }
  }

  // ======= Reduce over 16 column lanes (same row), store joint output ========
  float bb2 = bb2b[0];
#pragma unroll
  for (int rt = 0; rt < 2; ++rt)
#pragma unroll
    for (int i = 0; i < 4; ++i) {
      float v = pj[rt][i] + pb[rt][i];
      v += __shfl_xor(v, 1);
      v += __shfl_xor(v, 2);
      v += __shfl_xor(v, 4);
      v += __shfl_xor(v, 8);
      if (l15 == 0) out[m0 + rt * 16 + quad * 4 + i] = v + bb2;
    }
}

// ---------------------------------------------------------------------------
extern "C" void kernel_launch(void* const* d_in, const int* in_sizes, int n_in,
                              void* d_out, int out_size, void* d_ws, size_t ws_size,
                              hipStream_t stream) {
  const float* q    = (const float*)d_in[0];
  const float* st   = (const float*)d_in[1];
  const float* w1a  = (const float*)d_in[2];
  const float* b1a  = (const float*)d_in[3];
  const float* w1b  = (const float*)d_in[4];
  const float* b1b  = (const float*)d_in[5];
  const float* w2a  = (const float*)d_in[6];
  const float* b2a  = (const float*)d_in[7];
  const float* w2b  = (const float*)d_in[8];
  const float* b2b  = (const float*)d_in[9];
  const float* wb1  = (const float*)d_in[10];
  const float* bb1  = (const float*)d_in[11];
  const float* wb2a = (const float*)d_in[12];
  const float* bb2a = (const float*)d_in[13];
  const float* wb2b = (const float*)d_in[14];
  const float* bb2b = (const float*)d_in[15];
  bf16_t* W = (bf16_t*)d_ws;

  hipLaunchKernelGGL(prep_weights, dim3((WS_ELEMS + 255) / 256), dim3(256), 0, stream,
                     w1a, w1b, w2a, w2b, wb1, wb2a, W);
  hipLaunchKernelGGL(mixing_fused, dim3(NTOT / 128), dim3(256), 0, stream,
                     q, st, W, b1a, b1b, b2a, b2b, bb1, bb2a, wb2b, bb2b, (float*)d_out);
}

// Round 6
// 332.298 us; speedup vs baseline: 1.3640x; 1.3640x over previous
//
#include <hip/hip_runtime.h>
#include <math.h>

typedef __bf16 bf16_t;
typedef bf16_t bf16x8 __attribute__((ext_vector_type(8)));
typedef float  floatx4 __attribute__((ext_vector_type(4)));

#define MFMA16(a, b, c) __builtin_amdgcn_mfma_f32_16x16x32_bf16((a), (b), (c), 0, 0, 0)

// Problem constants
constexpr int NTOT = 256 * 512;   // 131072 samples
constexpr int CDIM = 256;         // K for all GEMMs

// ws: flat stream of 88 weight tiles in USE ORDER; tile = 16 output cols x 256 k
// in MFMA B-fragment order: tile[ks][lane][j] (8 KB). Wave B-load = contiguous 1 KB.
//   tiles  0..15 : w1a   (phase A,  groups  0..7)
//   tiles 16..19 : wb1   (phase B1, groups  8..9)
//   tiles 20..51 : w1b   (phase B2, groups 10..25)
//   tiles 52..67 : w2a   (phase C,  groups 26..33)
//   tiles 68..71 : w2b   (phase D,  groups 34..35)
//   tiles 72..87 : wb2a  (phase E,  groups 36..43)
constexpr int N_TILES  = 88;
constexpr int WS_ELEMS = N_TILES * 4096;

// ---------------------------------------------------------------------------
__global__ void prep_weights(const float* __restrict__ w1a, const float* __restrict__ w1b,
                             const float* __restrict__ w2a, const float* __restrict__ w2b,
                             const float* __restrict__ wb1, const float* __restrict__ wb2a,
                             bf16_t* __restrict__ ws) {
  int idx = blockIdx.x * 256 + threadIdx.x;
  if (idx >= WS_ELEMS) return;
  int t   = idx >> 12;       // tile
  int rel = idx & 4095;
  const float* src; int dout; int ct;
  if      (t < 16) { src = w1a;  dout = 256; ct = t; }
  else if (t < 20) { src = wb1;  dout = 64;  ct = t - 16; }
  else if (t < 52) { src = w1b;  dout = 512; ct = t - 20; }
  else if (t < 68) { src = w2a;  dout = 256; ct = t - 52; }
  else if (t < 72) { src = w2b;  dout = 64;  ct = t - 68; }
  else             { src = wb2a; dout = 256; ct = t - 72; }
  int j    = rel & 7;
  int lane = (rel >> 3) & 63;
  int ks   = rel >> 9;
  int o = ct * 16 + (lane & 15);
  int k = ks * 32 + (lane >> 4) * 8 + j;
  ws[idx] = (bf16_t)src[(size_t)k * dout + o];
}

// async global->LDS, 16 B per lane; LDS dest = wave-uniform base + lane*16
__device__ __forceinline__ void gload_lds16(const bf16_t* g, bf16_t* l) {
  __builtin_amdgcn_global_load_lds(
      (const __attribute__((address_space(1))) unsigned int*)g,
      (__attribute__((address_space(3))) unsigned int*)l, 16, 0, 0);
}

// ---------------------------------------------------------------------------
// Block = 4 waves = 128 rows, grid = 1024. Weight tiles staged once per block
// into LDS via global_load_lds (L2 weight traffic /4), double-buffered 16 KB
// groups. Schedule per group:  __syncthreads(); stage(g+1); compute(g)
// (the s_waitcnt vmcnt(0) before s_barrier drains stage(g), which had a full
// compute-group in flight -> ~free).
//
// CRITICAL (R3-R5 post-mortem): every register array (sA, hA, hid, pj, pb)
// must be indexed ONLY with compile-time constants, else LLVM demotes it to
// scratch (observed as 131-256 MB WRITE_SIZE). Hence full unrolling below.
// ---------------------------------------------------------------------------
__global__ __launch_bounds__(256, 2)
void mixing_fused(const float* __restrict__ q,     // [N,8]
                  const float* __restrict__ st,    // [N,256]
                  const bf16_t* __restrict__ W,    // ws (tile stream)
                  const float* __restrict__ b1a, const float* __restrict__ b1b,
                  const float* __restrict__ b2a, const float* __restrict__ b2b,
                  const float* __restrict__ bb1,
                  const float* __restrict__ bb2a,
                  const float* __restrict__ wb2b, const float* __restrict__ bb2b,
                  float* __restrict__ out) {
  __shared__ __align__(16) bf16_t wbuf[2][8192];     // 2 x 16 KB weight groups
  __shared__ __align__(16) bf16_t t_s[4][2][32][36]; // per-wave bounce (transpose)
  __shared__ __align__(16) float  q_s[4][256];       // per-wave q staging

  const int tid  = threadIdx.x;
  const int wid  = tid >> 6;
  const int lane = tid & 63;
  const int l15  = lane & 15;
  const int quad = lane >> 4;
  const int m0   = blockIdx.x * 128 + wid * 32;

  // wave-cooperative stage of group g (16 KB) into wbuf[g&1]
  auto stage = [&](int g) {
    const bf16_t* src = W + (size_t)g * 8192 + wid * 2048 + lane * 8;
    bf16_t* dst = &wbuf[g & 1][wid * 2048];
#pragma unroll
    for (int i = 0; i < 4; ++i)
      gload_lds16(src + i * 512, dst + i * 512);
  };

  // ---- wave-local q staging ----
  *(float4*)&q_s[wid][lane * 4] = *(const float4*)(q + (size_t)m0 * 8 + lane * 4);

  // ---- st A-fragments straight from global (coalesced), cvt to bf16 ----
  bf16x8 sA[2][8];
#pragma unroll
  for (int rt = 0; rt < 2; ++rt) {
    const float* rp = st + (size_t)(m0 + rt * 16 + l15) * CDIM;
#pragma unroll
    for (int ks = 0; ks < 8; ++ks) {
      int k0 = ks * 32 + quad * 8;
      float4 f0 = *(const float4*)(rp + k0);
      float4 f1 = *(const float4*)(rp + k0 + 4);
      bf16x8 v;
      v[0] = (bf16_t)f0.x; v[1] = (bf16_t)f0.y; v[2] = (bf16_t)f0.z; v[3] = (bf16_t)f0.w;
      v[4] = (bf16_t)f1.x; v[5] = (bf16_t)f1.y; v[6] = (bf16_t)f1.z; v[7] = (bf16_t)f1.w;
      sA[rt][ks] = v;
    }
  }

  // GEMM: 16-col tile h (0/1) of LDS group buffer `buf`, both row tiles.
  // A indexed only by constant kk (inner loop fully unrolled).
  auto gemmL = [&](int buf, int h, const bf16x8 (&A)[2][8], floatx4 (&acc)[2]) {
    floatx4 z = {0.f, 0.f, 0.f, 0.f};
    acc[0] = z; acc[1] = z;
#pragma unroll
    for (int kk = 0; kk < 8; ++kk) {
      bf16x8 b = *(const bf16x8*)&wbuf[buf][h * 4096 + kk * 512 + lane * 8];
      acc[0] = MFMA16(A[0][kk], b, acc[0]);
      acc[1] = MFMA16(A[1][kk], b, acc[1]);
    }
  };

  stage(0);

  bf16x8 hA[2][8];

  // ========= Phase A: H1 = elu(st @ w1a + b1a)   groups 0..7 (FULL unroll) ===
#pragma unroll
  for (int ks = 0; ks < 8; ++ks) {
    __syncthreads();
    stage(ks + 1);
    const int buf = ks & 1;
#pragma unroll
    for (int h = 0; h < 2; ++h) {
      int ct = 2 * ks + h;
      floatx4 acc[2];
      gemmL(buf, h, sA, acc);
      float bias = b1a[ct * 16 + l15];
#pragma unroll
      for (int rt = 0; rt < 2; ++rt)
#pragma unroll
        for (int i = 0; i < 4; ++i) {
          float v = acc[rt][i] + bias;
          v = v > 0.f ? v : (__expf(v) - 1.f);
          t_s[wid][buf][rt * 16 + quad * 4 + i][h * 16 + l15] = (bf16_t)v;
        }
    }
#pragma unroll
    for (int rt = 0; rt < 2; ++rt)
      hA[rt][ks] = *(const bf16x8*)&t_s[wid][buf][rt * 16 + l15][quad * 8];
  }

  // ========= Phase B1: hidden = st @ wb1 + bb1   groups 8..9 (FULL unroll) ===
  floatx4 hid[2][4];
#pragma unroll
  for (int gg = 0; gg < 2; ++gg) {
    __syncthreads();
    stage(9 + gg);
    const int buf = gg & 1;
#pragma unroll
    for (int h = 0; h < 2; ++h) {
      int et = 2 * gg + h;
      floatx4 acc[2];
      gemmL(buf, h, sA, acc);
      float bias = bb1[et * 16 + l15];
      hid[0][et] = acc[0] + bias;
      hid[1][et] = acc[1] + bias;
    }
  }

  // ==== Phase B2: W1 = |H1 @ w1b + b1b|; hidden += q.*W1   groups 10..25 =====
  // outer a runtime, inner fully unrolled so et (hid index) is constant.
#pragma unroll 1
  for (int a = 0; a < 8; ++a) {
#pragma unroll
    for (int g2 = 0; g2 < 2; ++g2) {
      const int idx = a * 2 + g2;          // 0..15
      __syncthreads();
      stage(11 + idx);
      const int buf = g2;                  // (10+idx)&1 == g2
#pragma unroll
      for (int h = 0; h < 2; ++h) {
        int ct = a * 4 + g2 * 2 + h;
        const int et = g2 * 2 + h;         // constant
        floatx4 acc[2];
        gemmL(buf, h, hA, acc);
        float bias = b1b[ct * 16 + l15];
#pragma unroll
        for (int rt = 0; rt < 2; ++rt)
#pragma unroll
          for (int i = 0; i < 4; ++i) {
            float w1v = fabsf(acc[rt][i] + bias);
            float qv  = q_s[wid][(rt * 16 + quad * 4 + i) * 8 + a];
            hid[rt][et][i] += qv * w1v;
          }
      }
    }
  }
  // relu
#pragma unroll
  for (int rt = 0; rt < 2; ++rt)
#pragma unroll
    for (int et = 0; et < 4; ++et)
#pragma unroll
      for (int i = 0; i < 4; ++i) hid[rt][et][i] = fmaxf(hid[rt][et][i], 0.f);

  // ========= Phase C: H2 = elu(st @ w2a + b2a)  groups 26..33 (FULL unroll) ==
#pragma unroll
  for (int ks = 0; ks < 8; ++ks) {
    __syncthreads();
    stage(27 + ks);
    const int buf = ks & 1;
#pragma unroll
    for (int h = 0; h < 2; ++h) {
      int ct = 2 * ks + h;
      floatx4 acc[2];
      gemmL(buf, h, sA, acc);
      float bias = b2a[ct * 16 + l15];
#pragma unroll
      for (int rt = 0; rt < 2; ++rt)
#pragma unroll
        for (int i = 0; i < 4; ++i) {
          float v = acc[rt][i] + bias;
          v = v > 0.f ? v : (__expf(v) - 1.f);
          t_s[wid][buf][rt * 16 + quad * 4 + i][h * 16 + l15] = (bf16_t)v;
        }
    }
#pragma unroll
    for (int rt = 0; rt < 2; ++rt)
      hA[rt][ks] = *(const bf16x8*)&t_s[wid][buf][rt * 16 + l15][quad * 8];
  }

  // ==== Phase D: W2 = |H2 @ w2b + b2b|; pj += hidden*W2   groups 34..35 ======
  float pj[2][4] = {{0.f, 0.f, 0.f, 0.f}, {0.f, 0.f, 0.f, 0.f}};
#pragma unroll
  for (int gg = 0; gg < 2; ++gg) {
    __syncthreads();
    stage(35 + gg);
    const int buf = gg & 1;
#pragma unroll
    for (int h = 0; h < 2; ++h) {
      int et = 2 * gg + h;
      floatx4 acc[2];
      gemmL(buf, h, hA, acc);
      float bias = b2b[et * 16 + l15];
#pragma unroll
      for (int rt = 0; rt < 2; ++rt)
#pragma unroll
        for (int i = 0; i < 4; ++i) {
          float w2v = fabsf(acc[rt][i] + bias);
          pj[rt][i] += hid[rt][et][i] * w2v;
        }
    }
  }

  // == Phase E: HB = elu(st @ wb2a + bb2a); pb += HB*wb2b   groups 36..43 =====
  float pb[2][4] = {{0.f, 0.f, 0.f, 0.f}, {0.f, 0.f, 0.f, 0.f}};
#pragma unroll 1
  for (int gg = 0; gg < 8; ++gg) {
    __syncthreads();
    if (gg < 7) stage(37 + gg);
    const int buf = gg & 1;
#pragma unroll
    for (int h = 0; h < 2; ++h) {
      int ct = 2 * gg + h;
      floatx4 acc[2];
      gemmL(buf, h, sA, acc);
      float bias = bb2a[ct * 16 + l15];
      float wv   = wb2b[ct * 16 + l15];
#pragma unroll
      for (int rt = 0; rt < 2; ++rt)
#pragma unroll
        for (int i = 0; i < 4; ++i) {
          float v = acc[rt][i] + bias;
          v = v > 0.f ? v : (__expf(v) - 1.f);
          pb[rt][i] += v * wv;
        }
    }
  }

  // ======= Reduce over 16 column lanes (same row), store joint output ========
  float bb2 = bb2b[0];
#pragma unroll
  for (int rt = 0; rt < 2; ++rt)
#pragma unroll
    for (int i = 0; i < 4; ++i) {
      float v = pj[rt][i] + pb[rt][i];
      v += __shfl_xor(v, 1);
      v += __shfl_xor(v, 2);
      v += __shfl_xor(v, 4);
      v += __shfl_xor(v, 8);
      if (l15 == 0) out[m0 + rt * 16 + quad * 4 + i] = v + bb2;
    }
}

// ---------------------------------------------------------------------------
extern "C" void kernel_launch(void* const* d_in, const int* in_sizes, int n_in,
                              void* d_out, int out_size, void* d_ws, size_t ws_size,
                              hipStream_t stream) {
  const float* q    = (const float*)d_in[0];
  const float* st   = (const float*)d_in[1];
  const float* w1a  = (const float*)d_in[2];
  const float* b1a  = (const float*)d_in[3];
  const float* w1b  = (const float*)d_in[4];
  const float* b1b  = (const float*)d_in[5];
  const float* w2a  = (const float*)d_in[6];
  const float* b2a  = (const float*)d_in[7];
  const float* w2b  = (const float*)d_in[8];
  const float* b2b  = (const float*)d_in[9];
  const float* wb1  = (const float*)d_in[10];
  const float* bb1  = (const float*)d_in[11];
  const float* wb2a = (const float*)d_in[12];
  const float* bb2a = (const float*)d_in[13];
  const float* wb2b = (const float*)d_in[14];
  const float* bb2b = (const float*)d_in[15];
  bf16_t* W = (bf16_t*)d_ws;

  hipLaunchKernelGGL(prep_weights, dim3((WS_ELEMS + 255) / 256), dim3(256), 0, stream,
                     w1a, w1b, w2a, w2b, wb1, wb2a, W);
  hipLaunchKernelGGL(mixing_fused, dim3(NTOT / 128), dim3(256), 0, stream,
                     q, st, W, b1a, b1b, b2a, b2b, bb1, bb2a, wb2b, bb2b, (float*)d_out);
}